// Round 4
// baseline (20365.208 us; speedup 1.0000x reference)
//
#include <hip/hip_runtime.h>

// NeuralCDE: B=64,T=256,C=16,S=64,H=128.
// Dtype forensics (rounds 0-3): inputs fp32, output fp32 (the "(bf16" in the
// harness label is the tolerance family, not the dtype).
// R1 failed at absmax 1.195 with correct dtypes -> trajectory decorrelation.
// This round: FULL fp32 pipeline (accurate expf/log1pf/tanhf, no f16
// anywhere) to pin down precision-vs-structural. One persistent block per
// batch element (64 blocks x 512 threads); W0 in LDS, W1/W2 streamed fp32
// from L2 every stage.

typedef float float4v __attribute__((ext_vector_type(4)));

__device__ __forceinline__ float softplusf(float x) {
  // jax.nn.softplus = max(x,0) + log1p(exp(-|x|))
  return fmaxf(x, 0.f) + log1pf(expf(-fabsf(x)));
}

// out6 -> 3x3 rotation write for time index t. Called by all 512 threads.
__device__ __forceinline__ void emit_out(int tid, int t,
                                         const float* sY, const float* sRo,
                                         const float* sRob,
                                         float* __restrict__ outb,
                                         float* s6) {
  if (tid < 96) {
    int o = tid >> 4, ch = (tid & 15) * 4;
    const float* ro = sRo + o * 64 + ch;
    float p = ro[0] * sY[ch] + ro[1] * sY[ch + 1] + ro[2] * sY[ch + 2] +
              ro[3] * sY[ch + 3];
    p += __shfl_xor(p, 1);
    p += __shfl_xor(p, 2);
    p += __shfl_xor(p, 4);
    p += __shfl_xor(p, 8);
    if ((tid & 15) == 0) s6[o] = p + sRob[o];
  }
  __syncthreads();
  if (tid == 0) {
    float a1x = s6[0], a1y = s6[1], a1z = s6[2];
    float a2x = s6[3], a2y = s6[4], a2z = s6[5];
    float n1 = rsqrtf(a1x * a1x + a1y * a1y + a1z * a1z);
    float b1x = a1x * n1, b1y = a1y * n1, b1z = a1z * n1;
    float d = b1x * a2x + b1y * a2y + b1z * a2z;
    float px = a2x - d * b1x, py = a2y - d * b1y, pz = a2z - d * b1z;
    float n2 = rsqrtf(px * px + py * py + pz * pz);
    float b2x = px * n2, b2y = py * n2, b2z = pz * n2;
    float b3x = b1y * b2z - b1z * b2y;
    float b3y = b1z * b2x - b1x * b2z;
    float b3z = b1x * b2y - b1y * b2x;
    float* o = outb + (size_t)t * 9;
    // stack([b1,b2,b3], axis=-1): rows = xyz, cols = b1,b2,b3
    o[0] = b1x; o[1] = b2x; o[2] = b3x;
    o[3] = b1y; o[4] = b2y; o[5] = b3y;
    o[6] = b1z; o[7] = b2z; o[8] = b3z;
  }
}

__global__ __launch_bounds__(512) void cde_main(
    const float* __restrict__ xs,
    const float* __restrict__ icw0, const float* __restrict__ icb0,
    const float* __restrict__ icw1, const float* __restrict__ icb1,
    const float* __restrict__ icw2, const float* __restrict__ icb2,
    const float* __restrict__ vfw0, const float* __restrict__ vfb0,
    const float* __restrict__ vfw1, const float* __restrict__ vfb1,
    const float* __restrict__ vfw2, const float* __restrict__ vfb2,
    const float* __restrict__ row, const float* __restrict__ rob,
    float* __restrict__ out) {
  constexpr float Ac[6][5] = {
      {0.f, 0.f, 0.f, 0.f, 0.f},
      {0.161f, 0.f, 0.f, 0.f, 0.f},
      {-0.008480655492356989f, 0.335480655492357f, 0.f, 0.f, 0.f},
      {2.8971530571054935f, -6.359448489975075f, 4.3622954328695815f, 0.f, 0.f},
      {5.325864828439257f, -11.748883564062828f, 7.4955393428898365f,
       -0.09249506636175525f, 0.f},
      {5.86145544294642f, -12.92096931784711f, 8.159367898576159f,
       -0.071584973281401f, -0.028269050394068383f}};
  constexpr float SCv[6] = {0.f, 0.161f, 0.327f, 0.9f, 0.9800255409045097f, 1.f};
  constexpr float BWv[6] = {0.09646076681806523f, 0.01f, 0.4798896504144996f,
                            1.379008574103742f, -3.290069515436081f,
                            2.324710524099774f};

  const int tid = threadIdx.x;
  const int b = blockIdx.x;

  __shared__ __align__(16) float sW0[128 * 64];  // 32 KB, fp32
  __shared__ float sB0[128], sB1[128], sB2[1024];
  __shared__ float sRo[384];
  __shared__ float sRob[6];
  __shared__ float sY[64];
  __shared__ float sK[6][64];
  __shared__ __align__(16) float sYt[64];
  __shared__ __align__(16) float sH1[128];
  __shared__ __align__(16) float sH2[128];
  __shared__ float sDx[16];
  __shared__ float s6[6];
  __shared__ float sTA[128], sTB[128];

  for (int i = tid; i < 8192; i += 512) sW0[i] = vfw0[i];
  if (tid < 128) { sB0[tid] = vfb0[tid]; sB1[tid] = vfb1[tid]; }
  for (int i = tid; i < 1024; i += 512) sB2[i] = vfb2[i];
  if (tid < 384) sRo[tid] = row[tid];
  if (tid < 6) sRob[tid] = rob[tid];

  const float* Xb = xs + (size_t)b * 256 * 16;
  float* outb = out + (size_t)b * 256 * 9;

  __syncthreads();

  // ---- initial condition MLP (one-time) ----
  if (tid < 128) {
    float a = icb0[tid];
    const float* wr = icw0 + tid * 16;
#pragma unroll
    for (int k = 0; k < 16; ++k) a += wr[k] * Xb[k];
    sTA[tid] = softplusf(a);
  }
  __syncthreads();
  if (tid < 128) {
    float a = icb1[tid];
    const float* wr = icw1 + tid * 128;
    for (int k = 0; k < 128; ++k) a += wr[k] * sTA[k];
    sTB[tid] = softplusf(a);
  }
  __syncthreads();
  if (tid < 64) {
    float a = icb2[tid];
    const float* wr = icw2 + tid * 128;
    for (int k = 0; k < 128; ++k) a += wr[k] * sTB[k];
    sY[tid] = a;
  }
  __syncthreads();
  emit_out(tid, 0, sY, sRo, sRob, outb, s6);

  const float hstep = 1.f / 255.f;
  const float invh = 255.f;

  float xi = 0.f, xip1 = 0.f, di = 0.f, dip1 = 0.f;  // valid on tid 64..79

  for (int t = 0; t < 255; ++t) {
    if (tid >= 64 && tid < 80) {
      int c = tid - 64;
      xi = Xb[t * 16 + c];
      xip1 = Xb[(t + 1) * 16 + c];
      dip1 = (xip1 - xi) * invh;                               // dfull[t+1]
      di = (t == 0) ? dip1 : (xi - Xb[(t - 1) * 16 + c]) * invh;  // dfull[t]
    }
#pragma unroll 1
    for (int j = 0; j < 6; ++j) {
      // stage input y_j and dXdt(sc_j)
      if (tid < 64) {
        float yt = sY[tid];
#pragma unroll
        for (int m = 0; m < 5; ++m)
          if (m < j) yt += hstep * Ac[j][m] * sK[m][tid];
        sYt[tid] = yt;
      } else if (tid < 80) {
        float sc = SCv[j];
        float s2 = sc * sc;
        float d1 = (6.f * s2 - 6.f * sc) * invh;
        float d2 = 3.f * s2 - 4.f * sc + 1.f;
        float d4 = 3.f * s2 - 2.f * sc;
        sDx[tid - 64] = d1 * (xi - xip1) + d2 * di + d4 * dip1;
      }
      __syncthreads();
      // h1 = softplus(W0 @ y + b0): 128 outputs, 4 lanes each (16 floats ea)
      {
        int i = tid >> 2, q = tid & 3;
        const float4v* wr = (const float4v*)(sW0 + i * 64 + q * 16);
        const float4v* yv = (const float4v*)(sYt + q * 16);
        float p = 0.f;
#pragma unroll
        for (int kk = 0; kk < 4; ++kk) {
          float4v w = wr[kk], y = yv[kk];
          p += w.x * y.x + w.y * y.y + w.z * y.z + w.w * y.w;
        }
        p += __shfl_xor(p, 1);
        p += __shfl_xor(p, 2);
        if (q == 0) sH1[i] = softplusf(p + sB0[i]);
      }
      __syncthreads();
      // h2 = softplus(W1 @ h1 + b1): W1 streamed fp32 from L2
      {
        int i = tid >> 2, q = tid & 3;
        const float4v* wr = (const float4v*)(vfw1 + i * 128 + q * 32);
        const float4v* hv = (const float4v*)(sH1 + q * 32);
        float p = 0.f;
#pragma unroll
        for (int kk = 0; kk < 8; ++kk) {
          float4v w = wr[kk], y = hv[kk];
          p += w.x * y.x + w.y * y.y + w.z * y.z + w.w * y.w;
        }
        p += __shfl_xor(p, 1);
        p += __shfl_xor(p, 2);
        if (q == 0) sH2[i] = softplusf(p + sB1[i]);
      }
      __syncthreads();
      // A = tanh(W2 @ h2 + b2); k_j[s] = sum_c A[s*16+c] * dx[c]
      // W2 streamed fp32 from L2; 2 rows per thread.
      {
        int r0 = tid * 2, r1 = r0 + 1;
        const float4v* w0v = (const float4v*)(vfw2 + (size_t)r0 * 128);
        const float4v* w1v = (const float4v*)(vfw2 + (size_t)r1 * 128);
        const float4v* hv = (const float4v*)sH2;
        float p0 = 0.f, p1 = 0.f;
#pragma unroll
        for (int kk = 0; kk < 32; ++kk) {
          float4v h = hv[kk];
          float4v wa = w0v[kk];
          float4v wb = w1v[kk];
          p0 += wa.x * h.x + wa.y * h.y + wa.z * h.z + wa.w * h.w;
          p1 += wb.x * h.x + wb.y * h.y + wb.z * h.z + wb.w * h.w;
        }
        float f0 = tanhf(p0 + sB2[r0]) * sDx[r0 & 15];
        float f1 = tanhf(p1 + sB2[r1]) * sDx[r1 & 15];
        float p = f0 + f1;
        p += __shfl_xor(p, 1);
        p += __shfl_xor(p, 2);
        p += __shfl_xor(p, 4);
        if ((tid & 7) == 0) sK[j][tid >> 3] = p;
      }
      __syncthreads();
    }
    // y_{t+1} = y_t + h * sum BW_m k_m
    if (tid < 64) {
      float yn = sY[tid];
#pragma unroll
      for (int m = 0; m < 6; ++m) yn += hstep * BWv[m] * sK[m][tid];
      sY[tid] = yn;
    }
    __syncthreads();
    emit_out(tid, t + 1, sY, sRo, sRob, outb, s6);
  }
}

extern "C" void kernel_launch(void* const* d_in, const int* in_sizes, int n_in,
                              void* d_out, int out_size, void* d_ws,
                              size_t ws_size, hipStream_t stream) {
  (void)in_sizes; (void)n_in; (void)out_size; (void)d_ws; (void)ws_size;
  const float* xs   = (const float*)d_in[0];
  const float* icw0 = (const float*)d_in[1];
  const float* icb0 = (const float*)d_in[2];
  const float* icw1 = (const float*)d_in[3];
  const float* icb1 = (const float*)d_in[4];
  const float* icw2 = (const float*)d_in[5];
  const float* icb2 = (const float*)d_in[6];
  const float* vfw0 = (const float*)d_in[7];
  const float* vfb0 = (const float*)d_in[8];
  const float* vfw1 = (const float*)d_in[9];
  const float* vfb1 = (const float*)d_in[10];
  const float* vfw2 = (const float*)d_in[11];
  const float* vfb2 = (const float*)d_in[12];
  const float* row  = (const float*)d_in[13];
  const float* rob  = (const float*)d_in[14];

  hipLaunchKernelGGL(cde_main, dim3(64), dim3(512), 0, stream,
                     xs, icw0, icb0, icw1, icb1, icw2, icb2,
                     vfw0, vfb0, vfw1, vfb1, vfw2, vfb2, row, rob,
                     (float*)d_out);
}